// Round 7
// baseline (425.778 us; speedup 1.0000x reference)
//
#include <hip/hip_runtime.h>
#include <math.h>

// ---- problem constants (match reference) ----
#define NN   100000   // nodes
#define DD   128      // in_channels
#define EE   600000   // edges
#define EAD  16       // edge_attr dim
#define BB   50       // graphs
#define NPG  2000     // nodes per graph
#define KK   1000     // kept per graph
#define NKEEP (BB*KK) // 50000

// output layout (floats, concatenated in return order)
#define OFF_OEI    6400000
#define OFF_OEA    7600000
#define OFF_OBATCH 17200000
#define OFF_EMASK  17250000

#define NRED 240  // reduction blocks
#define SCAN_NB 98 // ceil(100000/1024)

// ============ K1: edge MLP -> ew, deg_w, deg_c ============
// k_node pattern: block = 64 edges; wave = 4 edge-groups x 16 j-groups; lane
// owns 4 edges x 8 j. Weight traffic via L1 VMEM (512B/edge) instead of LDS
// broadcast (8KB/edge, the v1 84us bottleneck). HISTORY: round-4 tried this
// with default launch_bounds -> allocator targeted 12 waves/SIMD, VGPR=40 for
// a ~90-float working set -> L2 spills, 90us. Round-5 added full unroll ->
// HBM spills, 554us. Fix: __launch_bounds__(256,2) (VGPR cap 256) + unroll 1.
// If VGPR comes back <=64, the allocator ignored the hint: abandon this path.
#define EB 64   // edges per block (EE % 64 == 0 -> no tail)
__global__ __launch_bounds__(256, 2) void k_edge_mlp(
    const float* __restrict__ edge_attr, const int* __restrict__ src,
    const float* __restrict__ We1, const float* __restrict__ be1,
    const float* __restrict__ We2, const float* __restrict__ be2,
    float* __restrict__ ew, float* __restrict__ deg_w, float* __restrict__ deg_c)
{
    __shared__ float ea[EB * 20];  // 5 KB, stride 20 -> conflict-free b128
    int tid = threadIdx.x;
    int wave = tid >> 6, lane = tid & 63;
    int ng = lane >> 4, jg = lane & 15;
    int ebase = blockIdx.x * EB;

    // stage 64 edge rows: thread t -> float4 slot t (row = t>>2, c = t&3).
    {
        int row = tid >> 2, c = tid & 3;
        *(float4*)(ea + row * 20 + c * 4) =
            *(const float4*)(edge_attr + (size_t)(ebase + row) * EAD + c * 4);
    }
    __syncthreads();

    int j0 = jg * 8;
    const float* xw = ea + (wave * 16 + ng * 4) * 20;  // my 4 edge rows

    float acc[4][8];
    #pragma unroll
    for (int i = 0; i < 4; i++)
        #pragma unroll
        for (int jj = 0; jj < 8; jj++) acc[i][jj] = 0.f;

    #pragma unroll 1
    for (int k = 0; k < EAD; k += 4) {
        float4 xv[4];
        #pragma unroll
        for (int i = 0; i < 4; i++) xv[i] = *(const float4*)(xw + i * 20 + k);
        float4 wv[4][2];
        #pragma unroll
        for (int kk = 0; kk < 4; kk++) {
            wv[kk][0] = *(const float4*)(We1 + (k + kk) * DD + j0);
            wv[kk][1] = *(const float4*)(We1 + (k + kk) * DD + j0 + 4);
        }
        #pragma unroll
        for (int i = 0; i < 4; i++) {
            const float xe[4] = {xv[i].x, xv[i].y, xv[i].z, xv[i].w};
            #pragma unroll
            for (int kk = 0; kk < 4; kk++) {
                acc[i][0] += xe[kk] * wv[kk][0].x;
                acc[i][1] += xe[kk] * wv[kk][0].y;
                acc[i][2] += xe[kk] * wv[kk][0].z;
                acc[i][3] += xe[kk] * wv[kk][0].w;
                acc[i][4] += xe[kk] * wv[kk][1].x;
                acc[i][5] += xe[kk] * wv[kk][1].y;
                acc[i][6] += xe[kk] * wv[kk][1].z;
                acc[i][7] += xe[kk] * wv[kk][1].w;
            }
        }
    }

    float4 b1a = *(const float4*)(be1 + j0), b1b = *(const float4*)(be1 + j0 + 4);
    float4 w2a = *(const float4*)(We2 + j0), w2b = *(const float4*)(We2 + j0 + 4);
    const float b1v[8] = {b1a.x,b1a.y,b1a.z,b1a.w, b1b.x,b1b.y,b1b.z,b1b.w};
    const float w2v[8] = {w2a.x,w2a.y,w2a.z,w2a.w, w2b.x,w2b.y,w2b.z,w2b.w};
    float bias2 = be2[0];

    #pragma unroll
    for (int i = 0; i < 4; i++) {
        float p = 0.f;
        #pragma unroll
        for (int jj = 0; jj < 8; jj++)
            p += fmaxf(acc[i][jj] + b1v[jj], 0.f) * w2v[jj];
        p += __shfl_xor(p, 1, 64);
        p += __shfl_xor(p, 2, 64);
        p += __shfl_xor(p, 4, 64);
        p += __shfl_xor(p, 8, 64);
        if (jg == 0) {
            int e = ebase + wave * 16 + ng * 4 + i;
            float a = p + bias2;
            float sp = fmaxf(a, 0.f) + log1pf(expf(-fabsf(a)));
            float w = sp + 1e-6f;
            ew[e] = w;
            int s = src[e];
            atomicAdd(&deg_w[s], w);
            atomicAdd(&deg_c[s], 1.0f);
        }
    }
}

// ============ K3a: per-1024-block exclusive scan of degree counts ============
__global__ __launch_bounds__(1024) void k_scan_block(
    const float* __restrict__ deg_c, int* __restrict__ scanned,
    int* __restrict__ blocksums)
{
    __shared__ int s[1024];
    int i = blockIdx.x * 1024 + threadIdx.x;
    int c = (i < NN) ? (int)deg_c[i] : 0;
    s[threadIdx.x] = c;
    __syncthreads();
    for (int off = 1; off < 1024; off <<= 1) {
        int v = (threadIdx.x >= off) ? s[threadIdx.x - off] : 0;
        __syncthreads();
        s[threadIdx.x] += v;
        __syncthreads();
    }
    if (i < NN) scanned[i] = s[threadIdx.x] - c; // exclusive
    if (threadIdx.x == 1023) blocksums[blockIdx.x] = s[1023];
}

// ============ K3b: scan the block sums (one block) ============
__global__ __launch_bounds__(128) void k_scan_top(int* __restrict__ blocksums)
{
    __shared__ int s[128];
    int c = (threadIdx.x < SCAN_NB) ? blocksums[threadIdx.x] : 0;
    s[threadIdx.x] = c;
    __syncthreads();
    for (int off = 1; off < 128; off <<= 1) {
        int v = (threadIdx.x >= off) ? s[threadIdx.x - off] : 0;
        __syncthreads();
        s[threadIdx.x] += v;
        __syncthreads();
    }
    if (threadIdx.x < SCAN_NB) blocksums[threadIdx.x] = s[threadIdx.x] - c; // exclusive
}

// ============ K3c: rowstart / cursor init + dis + new_id init (fused) ============
__global__ __launch_bounds__(256) void k_cursor(
    const int* __restrict__ scanned, const int* __restrict__ blocksums,
    const float* __restrict__ deg_w,
    int* __restrict__ rowstart, int* __restrict__ cur,
    float* __restrict__ dis, int* __restrict__ new_id)
{
    int n = blockIdx.x * 256 + threadIdx.x;
    if (n >= NN) return;
    int st = scanned[n] + blocksums[n >> 10];
    rowstart[n] = st;
    cur[n] = st;
    float d = deg_w[n];
    dis[n] = d > 0.f ? 1.f / sqrtf(d) : 0.f;
    new_id[n] = -1;
}

// ============ K3d: scatter edges into CSR buckets (dst + norm) ============
__global__ __launch_bounds__(256) void k_scatter(
    const int* __restrict__ src, const int* __restrict__ dst,
    const float* __restrict__ ew, const float* __restrict__ dis,
    int* __restrict__ cur, int* __restrict__ csr_dst, float* __restrict__ csr_w)
{
    int e = blockIdx.x * 256 + threadIdx.x;
    if (e >= EE) return;
    int s = src[e], d = dst[e];
    float w = dis[s] * ew[e] * dis[d];
    int pos = atomicAdd(&cur[s], 1);
    csr_dst[pos] = d;
    csr_w[pos] = w;
}

// ============ K3e: fused diffusion gather + cosine + log-degree ============
// XCD-aware swizzle: blockIdx%8 ~ XCD -> each XCD works a contiguous
// 12500-node slice (3.2 MB of x fits the 4 MB per-XCD L2).
__global__ __launch_bounds__(256) void k_gather_cos(
    const int* __restrict__ rowstart, const float* __restrict__ deg_c,
    const int* __restrict__ csr_dst, const float* __restrict__ csr_w,
    const float* __restrict__ x, float* __restrict__ raw0, float* __restrict__ raw2)
{
    int blk = blockIdx.x;                       // 25000 blocks
    int node = ((blk & 7) * 3125 + (blk >> 3)) * 4 + (threadIdx.x >> 6);
    int lane = threadIdx.x & 63;
    if (node >= NN) return;
    int start = rowstart[node];
    int deg = (int)deg_c[node];
    const float2* xp = (const float2*)x;
    float2 xn = xp[(size_t)node * 64 + lane];
    float2 acc = {0.f, 0.f};
    for (int base = 0; base < deg; base += 64) {
        int rem = deg - base; if (rem > 64) rem = 64;
        int md = 0; float mw = 0.f;
        if (lane < rem) {
            md = csr_dst[start + base + lane];
            mw = csr_w[start + base + lane];
        }
        int e = 0;
        for (; e + 4 <= rem; e += 4) {
            int d0 = __shfl(md, e, 64),   d1 = __shfl(md, e+1, 64);
            int d2 = __shfl(md, e+2, 64), d3 = __shfl(md, e+3, 64);
            float w0 = __shfl(mw, e, 64),   w1 = __shfl(mw, e+1, 64);
            float w2 = __shfl(mw, e+2, 64), w3 = __shfl(mw, e+3, 64);
            float2 v0 = xp[(size_t)d0 * 64 + lane];
            float2 v1 = xp[(size_t)d1 * 64 + lane];
            float2 v2 = xp[(size_t)d2 * 64 + lane];
            float2 v3 = xp[(size_t)d3 * 64 + lane];
            acc.x += w0 * v0.x; acc.y += w0 * v0.y;
            acc.x += w1 * v1.x; acc.y += w1 * v1.y;
            acc.x += w2 * v2.x; acc.y += w2 * v2.y;
            acc.x += w3 * v3.x; acc.y += w3 * v3.y;
        }
        for (; e < rem; e++) {
            int d = __shfl(md, e, 64);
            float w = __shfl(mw, e, 64);
            float2 v = xp[(size_t)d * 64 + lane];
            acc.x += w * v.x; acc.y += w * v.y;
        }
    }
    float dot = xn.x * acc.x + xn.y * acc.y;
    float nx  = xn.x * xn.x + xn.y * xn.y;
    float nd  = acc.x * acc.x + acc.y * acc.y;
    #pragma unroll
    for (int off = 32; off; off >>= 1) {
        dot += __shfl_xor(dot, off, 64);
        nx  += __shfl_xor(nx,  off, 64);
        nd  += __shfl_xor(nd,  off, 64);
    }
    if (lane == 0) {
        raw2[node] = dot / ((sqrtf(nx) + 1e-6f) * (sqrtf(nd) + 1e-6f));
        raw0[node] = logf((float)deg + 1.0f);
    }
}

// ============ K4: per-node feat MLP (register-blocked GEMM) ============
#define XSTR 132
__global__ __launch_bounds__(256) void k_node(
    const float* __restrict__ x,
    const float* __restrict__ W1, const float* __restrict__ b1,
    const float* __restrict__ W2, const float* __restrict__ b2,
    float* __restrict__ raw1)
{
    __shared__ float xs[64 * XSTR]; // 33.8 KB
    int wave = threadIdx.x >> 6, lane = threadIdx.x & 63;
    int ng = lane >> 4, jg = lane & 15;
    int blockBase = blockIdx.x * 64;

    #pragma unroll
    for (int it = 0; it < 8; it++) {
        int s = threadIdx.x + 256 * it;
        int row = s >> 5, c4 = s & 31;
        int gn = blockBase + row; if (gn >= NN) gn = NN - 1;
        *(float4*)(xs + row * XSTR + c4 * 4) =
            *(const float4*)(x + (size_t)gn * DD + c4 * 4);
    }
    __syncthreads();

    const float* xw = xs + (wave * 16 + ng * 4) * XSTR;
    int j0 = jg * 8;
    float acc[4][8];
    #pragma unroll
    for (int i = 0; i < 4; i++)
        #pragma unroll
        for (int jj = 0; jj < 8; jj++) acc[i][jj] = 0.f;

    for (int k = 0; k < DD; k += 4) {
        float4 xv[4];
        #pragma unroll
        for (int i = 0; i < 4; i++) xv[i] = *(const float4*)(xw + i * XSTR + k);
        float4 wv[4][2];
        #pragma unroll
        for (int kk = 0; kk < 4; kk++) {
            wv[kk][0] = *(const float4*)(W1 + (k + kk) * DD + j0);
            wv[kk][1] = *(const float4*)(W1 + (k + kk) * DD + j0 + 4);
        }
        #pragma unroll
        for (int i = 0; i < 4; i++) {
            const float xe[4] = {xv[i].x, xv[i].y, xv[i].z, xv[i].w};
            #pragma unroll
            for (int kk = 0; kk < 4; kk++) {
                acc[i][0] += xe[kk] * wv[kk][0].x;
                acc[i][1] += xe[kk] * wv[kk][0].y;
                acc[i][2] += xe[kk] * wv[kk][0].z;
                acc[i][3] += xe[kk] * wv[kk][0].w;
                acc[i][4] += xe[kk] * wv[kk][1].x;
                acc[i][5] += xe[kk] * wv[kk][1].y;
                acc[i][6] += xe[kk] * wv[kk][1].z;
                acc[i][7] += xe[kk] * wv[kk][1].w;
            }
        }
    }

    float4 b1a = *(const float4*)(b1 + j0), b1b = *(const float4*)(b1 + j0 + 4);
    float4 w2a = *(const float4*)(W2 + j0), w2b = *(const float4*)(W2 + j0 + 4);
    const float b1v[8] = {b1a.x,b1a.y,b1a.z,b1a.w, b1b.x,b1b.y,b1b.z,b1b.w};
    const float w2v[8] = {w2a.x,w2a.y,w2a.z,w2a.w, w2b.x,w2b.y,w2b.z,w2b.w};
    float bias2 = b2[0];
    #pragma unroll
    for (int i = 0; i < 4; i++) {
        float p = 0.f;
        #pragma unroll
        for (int jj = 0; jj < 8; jj++)
            p += fmaxf(acc[i][jj] + b1v[jj], 0.f) * w2v[jj];
        p += __shfl_xor(p, 1, 64);
        p += __shfl_xor(p, 2, 64);
        p += __shfl_xor(p, 4, 64);
        p += __shfl_xor(p, 8, 64);
        int node = blockBase + wave * 16 + ng * 4 + i;
        if (jg == 0 && node < NN) raw1[node] = p + bias2;
    }
}

// ============ K5: block-level f64 partial sums (sum, sumsq) x3 ============
__global__ __launch_bounds__(256) void k_reduce(
    const float* __restrict__ r0, const float* __restrict__ r1,
    const float* __restrict__ r2, double* __restrict__ partials)
{
    __shared__ double sd[256];
    double s[6] = {0,0,0,0,0,0};
    for (int n = blockIdx.x * 256 + threadIdx.x; n < NN; n += 256 * NRED) {
        double v0 = r0[n], v1 = r1[n], v2 = r2[n];
        s[0] += v0; s[1] += v0*v0;
        s[2] += v1; s[3] += v1*v1;
        s[4] += v2; s[5] += v2*v2;
    }
    for (int q = 0; q < 6; q++) {
        sd[threadIdx.x] = s[q];
        __syncthreads();
        for (int off = 128; off; off >>= 1) {
            if (threadIdx.x < off) sd[threadIdx.x] += sd[threadIdx.x + off];
            __syncthreads();
        }
        if (threadIdx.x == 0) partials[blockIdx.x * 6 + q] = sd[0];
        __syncthreads();
    }
}

// ============ K6: final stats -> mean, 1/(std+eps) per view ============
__global__ __launch_bounds__(256) void k_stats(const double* __restrict__ partials,
                                               float* __restrict__ stats)
{
    __shared__ double sd[256];
    __shared__ double sums[6];
    for (int q = 0; q < 6; q++) {
        sd[threadIdx.x] = (threadIdx.x < NRED) ? partials[threadIdx.x * 6 + q] : 0.0;
        __syncthreads();
        for (int off = 128; off; off >>= 1) {
            if (threadIdx.x < off) sd[threadIdx.x] += sd[threadIdx.x + off];
            __syncthreads();
        }
        if (threadIdx.x == 0) sums[q] = sd[0];
        __syncthreads();
    }
    if (threadIdx.x == 0) {
        for (int i = 0; i < 3; i++) {
            double sum = sums[2*i], sq = sums[2*i+1];
            double mean = sum / NN;
            double var = (sq - sum * sum / NN) / (NN - 1);
            double sdv = sqrt(var > 0 ? var : 0);
            stats[2*i]   = (float)mean;
            stats[2*i+1] = (float)(1.0 / (sdv + 1e-6));
        }
    }
}

// ============ K8: per-graph score (fused) + top-K bitonic sort ============
__global__ __launch_bounds__(1024) void k_topk(
    const float* __restrict__ r0, const float* __restrict__ r1,
    const float* __restrict__ r2, const float* __restrict__ stats,
    const float* __restrict__ vw, float* __restrict__ score,
    int* __restrict__ keep, int* __restrict__ new_id, float* __restrict__ obatch)
{
    __shared__ unsigned long long keys[2048];
    int b = blockIdx.x;
    unsigned t = threadIdx.x;
    float m0 = stats[0], is0 = stats[1];
    float m1 = stats[2], is1 = stats[3];
    float m2 = stats[4], is2 = stats[5];
    float v0 = vw[0], v1 = vw[1], v2 = vw[2];
    for (unsigned i = t; i < 2048; i += 1024) {
        unsigned long long kk = 0ull;
        if (i < NPG) {
            int n = b * NPG + (int)i;
            float z0 = (r0[n] - m0) * is0;
            float z1 = (r1[n] - m1) * is1;
            float z2 = (r2[n] - m2) * is2;
            float r = z0 * v0 + z1 * v1 + z2 * v2;
            float sc = 1.f / (1.f + expf(-r));
            score[n] = sc;
            kk = ((unsigned long long)__float_as_uint(sc) << 32)
               | (unsigned long long)(0xFFFFFFFFu - i);
        }
        keys[i] = kk;
    }
    __syncthreads();
    for (unsigned k = 2; k <= 2048; k <<= 1) {
        for (unsigned j = k >> 1; j > 0; j >>= 1) {
            unsigned i = ((t & ~(j - 1)) << 1) | (t & (j - 1));
            unsigned p = i | j;
            unsigned long long a = keys[i], c = keys[p];
            bool up = ((i & k) == 0);
            if ((a < c) == up) { keys[i] = c; keys[p] = a; }
            __syncthreads();
        }
    }
    if (t < KK) {
        unsigned long long kk = keys[t];
        unsigned li = 0xFFFFFFFFu - (unsigned)(kk & 0xFFFFFFFFu);
        int node = b * NPG + (int)li;
        int j = b * KK + (int)t;
        keep[j] = node;
        new_id[node] = j;
        obatch[j] = (float)b;
    }
}

// ============ K9: out_x = x[keep] * score[keep] ============
__global__ __launch_bounds__(128) void k_outx(
    const float* __restrict__ x, const float* __restrict__ score,
    const int* __restrict__ keep, float* __restrict__ out_x)
{
    int j = blockIdx.x;
    int node = keep[j];
    float s = score[node];
    out_x[(size_t)j * DD + threadIdx.x] = x[(size_t)node * DD + threadIdx.x] * s;
}

// ============ K10: fused edge mask + new edge_index + masked edge_attr ============
__global__ __launch_bounds__(256) void k_edges_attr(
    const int* __restrict__ src, const int* __restrict__ dst,
    const int* __restrict__ new_id, const float* __restrict__ edge_attr,
    float* __restrict__ oei, float* __restrict__ emask, float* __restrict__ oea)
{
    int idx = blockIdx.x * 256 + threadIdx.x;
    if (idx >= EE * 4) return;
    int e = idx >> 2;
    int ns = new_id[src[e]], nd = new_id[dst[e]];
    bool m = (ns >= 0) && (nd >= 0);
    float mm = m ? 1.f : 0.f;
    float4 v = ((const float4*)edge_attr)[idx];
    float4 o; o.x = v.x*mm; o.y = v.y*mm; o.z = v.z*mm; o.w = v.w*mm;
    ((float4*)oea)[idx] = o;
    if ((idx & 3) == 0) {
        oei[e]      = m ? (float)ns : 0.f;
        oei[EE + e] = m ? (float)nd : 0.f;
        emask[e]    = mm;
    }
}

extern "C" void kernel_launch(void* const* d_in, const int* in_sizes, int n_in,
                              void* d_out, int out_size, void* d_ws, size_t ws_size,
                              hipStream_t stream) {
    const float* x         = (const float*)d_in[0];
    const int*   edge_idx  = (const int*)d_in[1];
    const float* edge_attr = (const float*)d_in[2];
    const float* W1  = (const float*)d_in[4];
    const float* b1  = (const float*)d_in[5];
    const float* W2  = (const float*)d_in[6];
    const float* b2  = (const float*)d_in[7];
    const float* We1 = (const float*)d_in[8];
    const float* be1 = (const float*)d_in[9];
    const float* We2 = (const float*)d_in[10];
    const float* be2 = (const float*)d_in[11];
    const float* vw  = (const float*)d_in[12];

    const int* src = edge_idx;
    const int* dst = edge_idx + EE;

    float* out    = (float*)d_out;
    float* out_x  = out;
    float* oei    = out + OFF_OEI;
    float* oea    = out + OFF_OEA;
    float* obatch = out + OFF_OBATCH;
    float* emask  = out + OFF_EMASK;

    // scratch inside d_out (dead before any output writer runs)
    int*   csr_dst   = (int*)(out + 12800000);    // 600k
    float* csr_w     = out + 13400000;            // 600k
    int*   rowstart  = (int*)(out + 14000000);    // 100k
    int*   cur       = (int*)(out + 14100000);    // 100k
    int*   scanned   = (int*)(out + 14200000);    // 100k
    int*   blocksums = (int*)(out + 14300000);    // 256

    // workspace layout (floats) — ~5.9 MB total
    float* ws     = (float*)d_ws;
    float* ew     = ws;                     // 600000
    float* deg_w  = ws + 600000;            // 100000
    float* deg_c  = ws + 700000;            // 100000 (adjacent to deg_w)
    float* dis    = ws + 800000;            // 100000
    float* score  = ws + 900000;            // 100000
    float* raw0   = ws + 1000000;           // 100000
    float* raw1   = ws + 1100000;           // 100000
    float* raw2   = ws + 1200000;           // 100000
    int*   keep   = (int*)(ws + 1300000);   // 50000
    int*   new_id = (int*)(ws + 1350000);   // 100000
    double* partials = (double*)(ws + 1450000); // NRED*6 doubles
    float* stats  = ws + 1450000 + 2 * 6 * NRED; // 6 floats

    hipMemsetAsync(deg_w, 0, 2 * NN * sizeof(float), stream); // deg_w + deg_c

    k_edge_mlp<<<EE / EB, 256, 0, stream>>>(edge_attr, src, We1, be1,
                                            We2, be2, ew, deg_w, deg_c);
    // CSR build (k_cursor also computes dis and inits new_id = -1)
    k_scan_block<<<SCAN_NB, 1024, 0, stream>>>(deg_c, scanned, blocksums);
    k_scan_top<<<1, 128, 0, stream>>>(blocksums);
    k_cursor<<<(NN + 255) / 256, 256, 0, stream>>>(scanned, blocksums, deg_w,
                                                   rowstart, cur, dis, new_id);
    k_scatter<<<(EE + 255) / 256, 256, 0, stream>>>(src, dst, ew, dis, cur, csr_dst, csr_w);
    // fused diffusion gather + cosine + log-degree (x_diff never materialized)
    k_gather_cos<<<(NN * 64 + 255) / 256, 256, 0, stream>>>(rowstart, deg_c, csr_dst,
                                                            csr_w, x, raw0, raw2);
    k_node<<<(NN + 63) / 64, 256, 0, stream>>>(x, W1, b1, W2, b2, raw1);
    k_reduce<<<NRED, 256, 0, stream>>>(raw0, raw1, raw2, partials);
    k_stats<<<1, 256, 0, stream>>>(partials, stats);
    k_topk<<<BB, 1024, 0, stream>>>(raw0, raw1, raw2, stats, vw, score,
                                    keep, new_id, obatch);
    k_outx<<<NKEEP, 128, 0, stream>>>(x, score, keep, out_x);
    k_edges_attr<<<(EE * 4 + 255) / 256, 256, 0, stream>>>(src, dst, new_id,
                                                           edge_attr, oei, emask, oea);
}

// Round 8
// 418.632 us; speedup vs baseline: 1.0171x; 1.0171x over previous
//
#include <hip/hip_runtime.h>
#include <math.h>

// ---- problem constants (match reference) ----
#define NN   100000   // nodes
#define DD   128      // in_channels
#define EE   600000   // edges
#define EAD  16       // edge_attr dim
#define BB   50       // graphs
#define NPG  2000     // nodes per graph
#define KK   1000     // kept per graph
#define NKEEP (BB*KK) // 50000

// output layout (floats, concatenated in return order)
#define OFF_OEI    6400000
#define OFF_OEA    7600000
#define OFF_OBATCH 17200000
#define OFF_EMASK  17250000

#define NRED 240  // reduction blocks
#define SCAN_NB 98 // ceil(100000/1024)

// ============ K1: edge MLP -> ew, deg_w, deg_c ============
// ROUND-1 PROVEN VERSION (81us, reproduced 3x). 1 thread = 1 edge (all 128 j);
// edge_attr tile in LDS (stride 20, conflict-free b128 rows); We1^T broadcast
// from LDS. VGPR 48, no spills. DS-issue-bound (~8 b128/edge) — structural
// floor at 1 edge/thread. Rounds 2-5,7 alternatives all lost to the register
// allocator (VGPR clamped to 32-48 for 60-90-float working sets -> spill slop;
// launch_bounds hints ignored). DO NOT restructure this kernel again.
#define EASTR 20
__global__ __launch_bounds__(256) void k_edge_mlp(
    const float* __restrict__ edge_attr, const int* __restrict__ src,
    const float* __restrict__ We1, const float* __restrict__ be1,
    const float* __restrict__ We2, const float* __restrict__ be2,
    float* __restrict__ ew, float* __restrict__ deg_w, float* __restrict__ deg_c)
{
    __shared__ float ea[256 * EASTR];  // 20.5 KB
    __shared__ float wt[2048];         // wt[j*16+k] = We1[k][j]  (8 KB)
    __shared__ float b1s[128];
    __shared__ float w2s[128];
    int tid = threadIdx.x;
    int ebase = blockIdx.x * 256;

    // stage We1^T: thread j (j<128) reads column j coalesced, writes row j*16
    if (tid < 128) {
        float tmp[16];
        #pragma unroll
        for (int k = 0; k < 16; k++) tmp[k] = We1[k * DD + tid];
        #pragma unroll
        for (int c = 0; c < 4; c++)
            *(float4*)(wt + tid * 16 + c * 4) =
                make_float4(tmp[4*c], tmp[4*c+1], tmp[4*c+2], tmp[4*c+3]);
        b1s[tid] = be1[tid];
        w2s[tid] = We2[tid];
    }
    // stage edge-attr tile (coalesced float4)
    #pragma unroll
    for (int it = 0; it < 4; it++) {
        int idx = tid + 256 * it;                 // float4 slot 0..1023
        long long g = (long long)ebase * 4 + idx;
        long long maxg = (long long)EE * 4;
        if (g >= maxg) g = maxg - 1;
        float4 v = ((const float4*)edge_attr)[g];
        int le = idx >> 2, c = idx & 3;
        *(float4*)(ea + le * EASTR + c * 4) = v;
    }
    __syncthreads();

    // own edge row -> 16 VGPRs (stride-20 b128: conflict-free)
    float av[16];
    {
        const float* a = ea + tid * EASTR;
        float4 a0 = *(const float4*)(a);
        float4 a1 = *(const float4*)(a + 4);
        float4 a2 = *(const float4*)(a + 8);
        float4 a3 = *(const float4*)(a + 12);
        av[0]=a0.x; av[1]=a0.y; av[2]=a0.z; av[3]=a0.w;
        av[4]=a1.x; av[5]=a1.y; av[6]=a1.z; av[7]=a1.w;
        av[8]=a2.x; av[9]=a2.y; av[10]=a2.z; av[11]=a2.w;
        av[12]=a3.x; av[13]=a3.y; av[14]=a3.z; av[15]=a3.w;
    }

    float acc = 0.f;
    #pragma unroll 4
    for (int j = 0; j < DD; j++) {
        float4 w0 = *(const float4*)(wt + j * 16);
        float4 w1 = *(const float4*)(wt + j * 16 + 4);
        float4 w2 = *(const float4*)(wt + j * 16 + 8);
        float4 w3 = *(const float4*)(wt + j * 16 + 12);
        float h = b1s[j];
        h += av[0]*w0.x;  h += av[1]*w0.y;  h += av[2]*w0.z;  h += av[3]*w0.w;
        h += av[4]*w1.x;  h += av[5]*w1.y;  h += av[6]*w1.z;  h += av[7]*w1.w;
        h += av[8]*w2.x;  h += av[9]*w2.y;  h += av[10]*w2.z; h += av[11]*w2.w;
        h += av[12]*w3.x; h += av[13]*w3.y; h += av[14]*w3.z; h += av[15]*w3.w;
        acc += fmaxf(h, 0.f) * w2s[j];
    }

    int e = ebase + tid;
    if (e < EE) {
        float a = acc + be2[0];
        float sp = fmaxf(a, 0.f) + log1pf(expf(-fabsf(a)));
        float w = sp + 1e-6f;
        ew[e] = w;
        int s = src[e];
        atomicAdd(&deg_w[s], w);
        atomicAdd(&deg_c[s], 1.0f);
    }
}

// ============ K3a: per-1024-block exclusive scan of degree counts ============
__global__ __launch_bounds__(1024) void k_scan_block(
    const float* __restrict__ deg_c, int* __restrict__ scanned,
    int* __restrict__ blocksums)
{
    __shared__ int s[1024];
    int i = blockIdx.x * 1024 + threadIdx.x;
    int c = (i < NN) ? (int)deg_c[i] : 0;
    s[threadIdx.x] = c;
    __syncthreads();
    for (int off = 1; off < 1024; off <<= 1) {
        int v = (threadIdx.x >= off) ? s[threadIdx.x - off] : 0;
        __syncthreads();
        s[threadIdx.x] += v;
        __syncthreads();
    }
    if (i < NN) scanned[i] = s[threadIdx.x] - c; // exclusive
    if (threadIdx.x == 1023) blocksums[blockIdx.x] = s[1023];
}

// ============ K3b: scan the block sums (one block) ============
__global__ __launch_bounds__(128) void k_scan_top(int* __restrict__ blocksums)
{
    __shared__ int s[128];
    int c = (threadIdx.x < SCAN_NB) ? blocksums[threadIdx.x] : 0;
    s[threadIdx.x] = c;
    __syncthreads();
    for (int off = 1; off < 128; off <<= 1) {
        int v = (threadIdx.x >= off) ? s[threadIdx.x - off] : 0;
        __syncthreads();
        s[threadIdx.x] += v;
        __syncthreads();
    }
    if (threadIdx.x < SCAN_NB) blocksums[threadIdx.x] = s[threadIdx.x] - c; // exclusive
}

// ============ K3c: rowstart / cursor init + dis + new_id init (fused) ============
__global__ __launch_bounds__(256) void k_cursor(
    const int* __restrict__ scanned, const int* __restrict__ blocksums,
    const float* __restrict__ deg_w,
    int* __restrict__ rowstart, int* __restrict__ cur,
    float* __restrict__ dis, int* __restrict__ new_id)
{
    int n = blockIdx.x * 256 + threadIdx.x;
    if (n >= NN) return;
    int st = scanned[n] + blocksums[n >> 10];
    rowstart[n] = st;
    cur[n] = st;
    float d = deg_w[n];
    dis[n] = d > 0.f ? 1.f / sqrtf(d) : 0.f;
    new_id[n] = -1;
}

// ============ K3d: scatter edges into CSR buckets (dst + norm) ============
__global__ __launch_bounds__(256) void k_scatter(
    const int* __restrict__ src, const int* __restrict__ dst,
    const float* __restrict__ ew, const float* __restrict__ dis,
    int* __restrict__ cur, int* __restrict__ csr_dst, float* __restrict__ csr_w)
{
    int e = blockIdx.x * 256 + threadIdx.x;
    if (e >= EE) return;
    int s = src[e], d = dst[e];
    float w = dis[s] * ew[e] * dis[d];
    int pos = atomicAdd(&cur[s], 1);
    csr_dst[pos] = d;
    csr_w[pos] = w;
}

// ============ K3e: fused diffusion gather + cosine + log-degree ============
// XCD-aware swizzle: blockIdx%8 ~ XCD -> each XCD works a contiguous
// 12500-node slice (3.2 MB of x fits the 4 MB per-XCD L2).
__global__ __launch_bounds__(256) void k_gather_cos(
    const int* __restrict__ rowstart, const float* __restrict__ deg_c,
    const int* __restrict__ csr_dst, const float* __restrict__ csr_w,
    const float* __restrict__ x, float* __restrict__ raw0, float* __restrict__ raw2)
{
    int blk = blockIdx.x;                       // 25000 blocks
    int node = ((blk & 7) * 3125 + (blk >> 3)) * 4 + (threadIdx.x >> 6);
    int lane = threadIdx.x & 63;
    if (node >= NN) return;
    int start = rowstart[node];
    int deg = (int)deg_c[node];
    const float2* xp = (const float2*)x;
    float2 xn = xp[(size_t)node * 64 + lane];
    float2 acc = {0.f, 0.f};
    for (int base = 0; base < deg; base += 64) {
        int rem = deg - base; if (rem > 64) rem = 64;
        int md = 0; float mw = 0.f;
        if (lane < rem) {
            md = csr_dst[start + base + lane];
            mw = csr_w[start + base + lane];
        }
        int e = 0;
        for (; e + 4 <= rem; e += 4) {
            int d0 = __shfl(md, e, 64),   d1 = __shfl(md, e+1, 64);
            int d2 = __shfl(md, e+2, 64), d3 = __shfl(md, e+3, 64);
            float w0 = __shfl(mw, e, 64),   w1 = __shfl(mw, e+1, 64);
            float w2 = __shfl(mw, e+2, 64), w3 = __shfl(mw, e+3, 64);
            float2 v0 = xp[(size_t)d0 * 64 + lane];
            float2 v1 = xp[(size_t)d1 * 64 + lane];
            float2 v2 = xp[(size_t)d2 * 64 + lane];
            float2 v3 = xp[(size_t)d3 * 64 + lane];
            acc.x += w0 * v0.x; acc.y += w0 * v0.y;
            acc.x += w1 * v1.x; acc.y += w1 * v1.y;
            acc.x += w2 * v2.x; acc.y += w2 * v2.y;
            acc.x += w3 * v3.x; acc.y += w3 * v3.y;
        }
        for (; e < rem; e++) {
            int d = __shfl(md, e, 64);
            float w = __shfl(mw, e, 64);
            float2 v = xp[(size_t)d * 64 + lane];
            acc.x += w * v.x; acc.y += w * v.y;
        }
    }
    float dot = xn.x * acc.x + xn.y * acc.y;
    float nx  = xn.x * xn.x + xn.y * xn.y;
    float nd  = acc.x * acc.x + acc.y * acc.y;
    #pragma unroll
    for (int off = 32; off; off >>= 1) {
        dot += __shfl_xor(dot, off, 64);
        nx  += __shfl_xor(nx,  off, 64);
        nd  += __shfl_xor(nd,  off, 64);
    }
    if (lane == 0) {
        raw2[node] = dot / ((sqrtf(nx) + 1e-6f) * (sqrtf(nd) + 1e-6f));
        raw0[node] = logf((float)deg + 1.0f);
    }
}

// ============ K4: per-node feat MLP (register-blocked GEMM) ============
#define XSTR 132
__global__ __launch_bounds__(256) void k_node(
    const float* __restrict__ x,
    const float* __restrict__ W1, const float* __restrict__ b1,
    const float* __restrict__ W2, const float* __restrict__ b2,
    float* __restrict__ raw1)
{
    __shared__ float xs[64 * XSTR]; // 33.8 KB
    int wave = threadIdx.x >> 6, lane = threadIdx.x & 63;
    int ng = lane >> 4, jg = lane & 15;
    int blockBase = blockIdx.x * 64;

    #pragma unroll
    for (int it = 0; it < 8; it++) {
        int s = threadIdx.x + 256 * it;
        int row = s >> 5, c4 = s & 31;
        int gn = blockBase + row; if (gn >= NN) gn = NN - 1;
        *(float4*)(xs + row * XSTR + c4 * 4) =
            *(const float4*)(x + (size_t)gn * DD + c4 * 4);
    }
    __syncthreads();

    const float* xw = xs + (wave * 16 + ng * 4) * XSTR;
    int j0 = jg * 8;
    float acc[4][8];
    #pragma unroll
    for (int i = 0; i < 4; i++)
        #pragma unroll
        for (int jj = 0; jj < 8; jj++) acc[i][jj] = 0.f;

    for (int k = 0; k < DD; k += 4) {
        float4 xv[4];
        #pragma unroll
        for (int i = 0; i < 4; i++) xv[i] = *(const float4*)(xw + i * XSTR + k);
        float4 wv[4][2];
        #pragma unroll
        for (int kk = 0; kk < 4; kk++) {
            wv[kk][0] = *(const float4*)(W1 + (k + kk) * DD + j0);
            wv[kk][1] = *(const float4*)(W1 + (k + kk) * DD + j0 + 4);
        }
        #pragma unroll
        for (int i = 0; i < 4; i++) {
            const float xe[4] = {xv[i].x, xv[i].y, xv[i].z, xv[i].w};
            #pragma unroll
            for (int kk = 0; kk < 4; kk++) {
                acc[i][0] += xe[kk] * wv[kk][0].x;
                acc[i][1] += xe[kk] * wv[kk][0].y;
                acc[i][2] += xe[kk] * wv[kk][0].z;
                acc[i][3] += xe[kk] * wv[kk][0].w;
                acc[i][4] += xe[kk] * wv[kk][1].x;
                acc[i][5] += xe[kk] * wv[kk][1].y;
                acc[i][6] += xe[kk] * wv[kk][1].z;
                acc[i][7] += xe[kk] * wv[kk][1].w;
            }
        }
    }

    float4 b1a = *(const float4*)(b1 + j0), b1b = *(const float4*)(b1 + j0 + 4);
    float4 w2a = *(const float4*)(W2 + j0), w2b = *(const float4*)(W2 + j0 + 4);
    const float b1v[8] = {b1a.x,b1a.y,b1a.z,b1a.w, b1b.x,b1b.y,b1b.z,b1b.w};
    const float w2v[8] = {w2a.x,w2a.y,w2a.z,w2a.w, w2b.x,w2b.y,w2b.z,w2b.w};
    float bias2 = b2[0];
    #pragma unroll
    for (int i = 0; i < 4; i++) {
        float p = 0.f;
        #pragma unroll
        for (int jj = 0; jj < 8; jj++)
            p += fmaxf(acc[i][jj] + b1v[jj], 0.f) * w2v[jj];
        p += __shfl_xor(p, 1, 64);
        p += __shfl_xor(p, 2, 64);
        p += __shfl_xor(p, 4, 64);
        p += __shfl_xor(p, 8, 64);
        int node = blockBase + wave * 16 + ng * 4 + i;
        if (jg == 0 && node < NN) raw1[node] = p + bias2;
    }
}

// ============ K5: block-level f64 partial sums (sum, sumsq) x3 ============
__global__ __launch_bounds__(256) void k_reduce(
    const float* __restrict__ r0, const float* __restrict__ r1,
    const float* __restrict__ r2, double* __restrict__ partials)
{
    __shared__ double sd[256];
    double s[6] = {0,0,0,0,0,0};
    for (int n = blockIdx.x * 256 + threadIdx.x; n < NN; n += 256 * NRED) {
        double v0 = r0[n], v1 = r1[n], v2 = r2[n];
        s[0] += v0; s[1] += v0*v0;
        s[2] += v1; s[3] += v1*v1;
        s[4] += v2; s[5] += v2*v2;
    }
    for (int q = 0; q < 6; q++) {
        sd[threadIdx.x] = s[q];
        __syncthreads();
        for (int off = 128; off; off >>= 1) {
            if (threadIdx.x < off) sd[threadIdx.x] += sd[threadIdx.x + off];
            __syncthreads();
        }
        if (threadIdx.x == 0) partials[blockIdx.x * 6 + q] = sd[0];
        __syncthreads();
    }
}

// ============ K6: final stats -> mean, 1/(std+eps) per view ============
__global__ __launch_bounds__(256) void k_stats(const double* __restrict__ partials,
                                               float* __restrict__ stats)
{
    __shared__ double sd[256];
    __shared__ double sums[6];
    for (int q = 0; q < 6; q++) {
        sd[threadIdx.x] = (threadIdx.x < NRED) ? partials[threadIdx.x * 6 + q] : 0.0;
        __syncthreads();
        for (int off = 128; off; off >>= 1) {
            if (threadIdx.x < off) sd[threadIdx.x] += sd[threadIdx.x + off];
            __syncthreads();
        }
        if (threadIdx.x == 0) sums[q] = sd[0];
        __syncthreads();
    }
    if (threadIdx.x == 0) {
        for (int i = 0; i < 3; i++) {
            double sum = sums[2*i], sq = sums[2*i+1];
            double mean = sum / NN;
            double var = (sq - sum * sum / NN) / (NN - 1);
            double sdv = sqrt(var > 0 ? var : 0);
            stats[2*i]   = (float)mean;
            stats[2*i+1] = (float)(1.0 / (sdv + 1e-6));
        }
    }
}

// ============ K8: per-graph score (fused) + top-K bitonic sort ============
__global__ __launch_bounds__(1024) void k_topk(
    const float* __restrict__ r0, const float* __restrict__ r1,
    const float* __restrict__ r2, const float* __restrict__ stats,
    const float* __restrict__ vw, float* __restrict__ score,
    int* __restrict__ keep, int* __restrict__ new_id, float* __restrict__ obatch)
{
    __shared__ unsigned long long keys[2048];
    int b = blockIdx.x;
    unsigned t = threadIdx.x;
    float m0 = stats[0], is0 = stats[1];
    float m1 = stats[2], is1 = stats[3];
    float m2 = stats[4], is2 = stats[5];
    float v0 = vw[0], v1 = vw[1], v2 = vw[2];
    for (unsigned i = t; i < 2048; i += 1024) {
        unsigned long long kk = 0ull;
        if (i < NPG) {
            int n = b * NPG + (int)i;
            float z0 = (r0[n] - m0) * is0;
            float z1 = (r1[n] - m1) * is1;
            float z2 = (r2[n] - m2) * is2;
            float r = z0 * v0 + z1 * v1 + z2 * v2;
            float sc = 1.f / (1.f + expf(-r));
            score[n] = sc;
            kk = ((unsigned long long)__float_as_uint(sc) << 32)
               | (unsigned long long)(0xFFFFFFFFu - i);
        }
        keys[i] = kk;
    }
    __syncthreads();
    for (unsigned k = 2; k <= 2048; k <<= 1) {
        for (unsigned j = k >> 1; j > 0; j >>= 1) {
            unsigned i = ((t & ~(j - 1)) << 1) | (t & (j - 1));
            unsigned p = i | j;
            unsigned long long a = keys[i], c = keys[p];
            bool up = ((i & k) == 0);
            if ((a < c) == up) { keys[i] = c; keys[p] = a; }
            __syncthreads();
        }
    }
    if (t < KK) {
        unsigned long long kk = keys[t];
        unsigned li = 0xFFFFFFFFu - (unsigned)(kk & 0xFFFFFFFFu);
        int node = b * NPG + (int)li;
        int j = b * KK + (int)t;
        keep[j] = node;
        new_id[node] = j;
        obatch[j] = (float)b;
    }
}

// ============ K9: out_x = x[keep] * score[keep] (float4, 8 rows/block) ============
__global__ __launch_bounds__(256) void k_outx(
    const float* __restrict__ x, const float* __restrict__ score,
    const int* __restrict__ keep, float* __restrict__ out_x)
{
    int r = blockIdx.x * 8 + (threadIdx.x >> 5);   // kept-node row
    int c = threadIdx.x & 31;                      // float4 column
    if (r >= NKEEP) return;
    int node = keep[r];
    float s = score[node];
    float4 v = *(const float4*)(x + (size_t)node * DD + c * 4);
    float4 o; o.x = v.x*s; o.y = v.y*s; o.z = v.z*s; o.w = v.w*s;
    *(float4*)(out_x + (size_t)r * DD + c * 4) = o;
}

// ============ K10: fused edge mask + new edge_index + masked edge_attr ============
// 1 thread per EDGE: 2 new_id gathers (vs 8 in the per-float4 form), then a
// 64B contiguous copy. Wave footprint: 64 edges x 64B = 4KB, L1-line reuse
// across the 4 float4 iterations.
__global__ __launch_bounds__(256) void k_edges_attr(
    const int* __restrict__ src, const int* __restrict__ dst,
    const int* __restrict__ new_id, const float* __restrict__ edge_attr,
    float* __restrict__ oei, float* __restrict__ emask, float* __restrict__ oea)
{
    int e = blockIdx.x * 256 + threadIdx.x;
    if (e >= EE) return;
    int ns = new_id[src[e]], nd = new_id[dst[e]];
    bool m = (ns >= 0) && (nd >= 0);
    float mm = m ? 1.f : 0.f;
    const float4* in4 = (const float4*)edge_attr;
    float4* out4 = (float4*)oea;
    #pragma unroll
    for (int c = 0; c < 4; c++) {
        float4 v = in4[(size_t)e * 4 + c];
        float4 o; o.x = v.x*mm; o.y = v.y*mm; o.z = v.z*mm; o.w = v.w*mm;
        out4[(size_t)e * 4 + c] = o;
    }
    oei[e]      = m ? (float)ns : 0.f;
    oei[EE + e] = m ? (float)nd : 0.f;
    emask[e]    = mm;
}

extern "C" void kernel_launch(void* const* d_in, const int* in_sizes, int n_in,
                              void* d_out, int out_size, void* d_ws, size_t ws_size,
                              hipStream_t stream) {
    const float* x         = (const float*)d_in[0];
    const int*   edge_idx  = (const int*)d_in[1];
    const float* edge_attr = (const float*)d_in[2];
    const float* W1  = (const float*)d_in[4];
    const float* b1  = (const float*)d_in[5];
    const float* W2  = (const float*)d_in[6];
    const float* b2  = (const float*)d_in[7];
    const float* We1 = (const float*)d_in[8];
    const float* be1 = (const float*)d_in[9];
    const float* We2 = (const float*)d_in[10];
    const float* be2 = (const float*)d_in[11];
    const float* vw  = (const float*)d_in[12];

    const int* src = edge_idx;
    const int* dst = edge_idx + EE;

    float* out    = (float*)d_out;
    float* out_x  = out;
    float* oei    = out + OFF_OEI;
    float* oea    = out + OFF_OEA;
    float* obatch = out + OFF_OBATCH;
    float* emask  = out + OFF_EMASK;

    // scratch inside d_out (dead before any output writer runs)
    int*   csr_dst   = (int*)(out + 12800000);    // 600k
    float* csr_w     = out + 13400000;            // 600k
    int*   rowstart  = (int*)(out + 14000000);    // 100k
    int*   cur       = (int*)(out + 14100000);    // 100k
    int*   scanned   = (int*)(out + 14200000);    // 100k
    int*   blocksums = (int*)(out + 14300000);    // 256

    // workspace layout (floats) — ~5.9 MB total
    float* ws     = (float*)d_ws;
    float* ew     = ws;                     // 600000
    float* deg_w  = ws + 600000;            // 100000
    float* deg_c  = ws + 700000;            // 100000 (adjacent to deg_w)
    float* dis    = ws + 800000;            // 100000
    float* score  = ws + 900000;            // 100000
    float* raw0   = ws + 1000000;           // 100000
    float* raw1   = ws + 1100000;           // 100000
    float* raw2   = ws + 1200000;           // 100000
    int*   keep   = (int*)(ws + 1300000);   // 50000
    int*   new_id = (int*)(ws + 1350000);   // 100000
    double* partials = (double*)(ws + 1450000); // NRED*6 doubles
    float* stats  = ws + 1450000 + 2 * 6 * NRED; // 6 floats

    hipMemsetAsync(deg_w, 0, 2 * NN * sizeof(float), stream); // deg_w + deg_c

    k_edge_mlp<<<(EE + 255) / 256, 256, 0, stream>>>(edge_attr, src, We1, be1,
                                                     We2, be2, ew, deg_w, deg_c);
    // CSR build (k_cursor also computes dis and inits new_id = -1)
    k_scan_block<<<SCAN_NB, 1024, 0, stream>>>(deg_c, scanned, blocksums);
    k_scan_top<<<1, 128, 0, stream>>>(blocksums);
    k_cursor<<<(NN + 255) / 256, 256, 0, stream>>>(scanned, blocksums, deg_w,
                                                   rowstart, cur, dis, new_id);
    k_scatter<<<(EE + 255) / 256, 256, 0, stream>>>(src, dst, ew, dis, cur, csr_dst, csr_w);
    // fused diffusion gather + cosine + log-degree (x_diff never materialized)
    k_gather_cos<<<(NN * 64 + 255) / 256, 256, 0, stream>>>(rowstart, deg_c, csr_dst,
                                                            csr_w, x, raw0, raw2);
    k_node<<<(NN + 63) / 64, 256, 0, stream>>>(x, W1, b1, W2, b2, raw1);
    k_reduce<<<NRED, 256, 0, stream>>>(raw0, raw1, raw2, partials);
    k_stats<<<1, 256, 0, stream>>>(partials, stats);
    k_topk<<<BB, 1024, 0, stream>>>(raw0, raw1, raw2, stats, vw, score,
                                    keep, new_id, obatch);
    k_outx<<<(NKEEP + 7) / 8, 256, 0, stream>>>(x, score, keep, out_x);
    k_edges_attr<<<(EE + 255) / 256, 256, 0, stream>>>(src, dst, new_id,
                                                       edge_attr, oei, emask, oea);
}

// Round 9
// 417.835 us; speedup vs baseline: 1.0190x; 1.0019x over previous
//
#include <hip/hip_runtime.h>
#include <math.h>

// ---- problem constants (match reference) ----
#define NN   100000   // nodes
#define DD   128      // in_channels
#define EE   600000   // edges
#define EAD  16       // edge_attr dim
#define BB   50       // graphs
#define NPG  2000     // nodes per graph
#define KK   1000     // kept per graph
#define NKEEP (BB*KK) // 50000

// output layout (floats, concatenated in return order)
#define OFF_OEI    6400000
#define OFF_OEA    7600000
#define OFF_OBATCH 17200000
#define OFF_EMASK  17250000

#define NRED 240  // reduction blocks
#define SCAN_NB 98 // ceil(100000/1024)

// ============ K1: edge MLP -> ew, deg_w, deg_c ============
// ROUND-1 PROVEN VERSION (81us, reproduced 4x), now launched as TWO half-range
// dispatches (~41us each) so other kernels become visible in the rocprof top-5.
// DS-BW-bound (~8KB weight broadcast per edge, 4.9GB @ ~69TB/s = 71us floor at
// 1 edge/thread). Rounds 2-5,7 restructures all lost to the register allocator.
// DO NOT restructure; only the ne-parameterization changed here.
#define EASTR 20
__global__ __launch_bounds__(256) void k_edge_mlp(
    const float* __restrict__ edge_attr, const int* __restrict__ src,
    const float* __restrict__ We1, const float* __restrict__ be1,
    const float* __restrict__ We2, const float* __restrict__ be2,
    float* __restrict__ ew, float* __restrict__ deg_w, float* __restrict__ deg_c,
    int ne)
{
    __shared__ float ea[256 * EASTR];  // 20.5 KB
    __shared__ float wt[2048];         // wt[j*16+k] = We1[k][j]  (8 KB)
    __shared__ float b1s[128];
    __shared__ float w2s[128];
    int tid = threadIdx.x;
    int ebase = blockIdx.x * 256;

    // stage We1^T: thread j (j<128) reads column j coalesced, writes row j*16
    if (tid < 128) {
        float tmp[16];
        #pragma unroll
        for (int k = 0; k < 16; k++) tmp[k] = We1[k * DD + tid];
        #pragma unroll
        for (int c = 0; c < 4; c++)
            *(float4*)(wt + tid * 16 + c * 4) =
                make_float4(tmp[4*c], tmp[4*c+1], tmp[4*c+2], tmp[4*c+3]);
        b1s[tid] = be1[tid];
        w2s[tid] = We2[tid];
    }
    // stage edge-attr tile (coalesced float4)
    #pragma unroll
    for (int it = 0; it < 4; it++) {
        int idx = tid + 256 * it;                 // float4 slot 0..1023
        long long g = (long long)ebase * 4 + idx;
        long long maxg = (long long)ne * 4;
        if (g >= maxg) g = maxg - 1;
        float4 v = ((const float4*)edge_attr)[g];
        int le = idx >> 2, c = idx & 3;
        *(float4*)(ea + le * EASTR + c * 4) = v;
    }
    __syncthreads();

    // own edge row -> 16 VGPRs (stride-20 b128: conflict-free)
    float av[16];
    {
        const float* a = ea + tid * EASTR;
        float4 a0 = *(const float4*)(a);
        float4 a1 = *(const float4*)(a + 4);
        float4 a2 = *(const float4*)(a + 8);
        float4 a3 = *(const float4*)(a + 12);
        av[0]=a0.x; av[1]=a0.y; av[2]=a0.z; av[3]=a0.w;
        av[4]=a1.x; av[5]=a1.y; av[6]=a1.z; av[7]=a1.w;
        av[8]=a2.x; av[9]=a2.y; av[10]=a2.z; av[11]=a2.w;
        av[12]=a3.x; av[13]=a3.y; av[14]=a3.z; av[15]=a3.w;
    }

    float acc = 0.f;
    #pragma unroll 4
    for (int j = 0; j < DD; j++) {
        float4 w0 = *(const float4*)(wt + j * 16);
        float4 w1 = *(const float4*)(wt + j * 16 + 4);
        float4 w2 = *(const float4*)(wt + j * 16 + 8);
        float4 w3 = *(const float4*)(wt + j * 16 + 12);
        float h = b1s[j];
        h += av[0]*w0.x;  h += av[1]*w0.y;  h += av[2]*w0.z;  h += av[3]*w0.w;
        h += av[4]*w1.x;  h += av[5]*w1.y;  h += av[6]*w1.z;  h += av[7]*w1.w;
        h += av[8]*w2.x;  h += av[9]*w2.y;  h += av[10]*w2.z; h += av[11]*w2.w;
        h += av[12]*w3.x; h += av[13]*w3.y; h += av[14]*w3.z; h += av[15]*w3.w;
        acc += fmaxf(h, 0.f) * w2s[j];
    }

    int e = ebase + tid;
    if (e < ne) {
        float a = acc + be2[0];
        float sp = fmaxf(a, 0.f) + log1pf(expf(-fabsf(a)));
        float w = sp + 1e-6f;
        ew[e] = w;
        int s = src[e];
        atomicAdd(&deg_w[s], w);
        atomicAdd(&deg_c[s], 1.0f);
    }
}

// ============ K3a: per-1024-block exclusive scan of degree counts ============
__global__ __launch_bounds__(1024) void k_scan_block(
    const float* __restrict__ deg_c, int* __restrict__ scanned,
    int* __restrict__ blocksums)
{
    __shared__ int s[1024];
    int i = blockIdx.x * 1024 + threadIdx.x;
    int c = (i < NN) ? (int)deg_c[i] : 0;
    s[threadIdx.x] = c;
    __syncthreads();
    for (int off = 1; off < 1024; off <<= 1) {
        int v = (threadIdx.x >= off) ? s[threadIdx.x - off] : 0;
        __syncthreads();
        s[threadIdx.x] += v;
        __syncthreads();
    }
    if (i < NN) scanned[i] = s[threadIdx.x] - c; // exclusive
    if (threadIdx.x == 1023) blocksums[blockIdx.x] = s[1023];
}

// ============ K3b: scan the block sums (one block) ============
__global__ __launch_bounds__(128) void k_scan_top(int* __restrict__ blocksums)
{
    __shared__ int s[128];
    int c = (threadIdx.x < SCAN_NB) ? blocksums[threadIdx.x] : 0;
    s[threadIdx.x] = c;
    __syncthreads();
    for (int off = 1; off < 128; off <<= 1) {
        int v = (threadIdx.x >= off) ? s[threadIdx.x - off] : 0;
        __syncthreads();
        s[threadIdx.x] += v;
        __syncthreads();
    }
    if (threadIdx.x < SCAN_NB) blocksums[threadIdx.x] = s[threadIdx.x] - c; // exclusive
}

// ============ K3c: rowstart / cursor init + dis + new_id init (fused) ============
__global__ __launch_bounds__(256) void k_cursor(
    const int* __restrict__ scanned, const int* __restrict__ blocksums,
    const float* __restrict__ deg_w,
    int* __restrict__ rowstart, int* __restrict__ cur,
    float* __restrict__ dis, int* __restrict__ new_id)
{
    int n = blockIdx.x * 256 + threadIdx.x;
    if (n >= NN) return;
    int st = scanned[n] + blocksums[n >> 10];
    rowstart[n] = st;
    cur[n] = st;
    float d = deg_w[n];
    dis[n] = d > 0.f ? 1.f / sqrtf(d) : 0.f;
    new_id[n] = -1;
}

// ============ K3d: scatter edges into CSR buckets (dst + norm) ============
__global__ __launch_bounds__(256) void k_scatter(
    const int* __restrict__ src, const int* __restrict__ dst,
    const float* __restrict__ ew, const float* __restrict__ dis,
    int* __restrict__ cur, int* __restrict__ csr_dst, float* __restrict__ csr_w)
{
    int e = blockIdx.x * 256 + threadIdx.x;
    if (e >= EE) return;
    int s = src[e], d = dst[e];
    float w = dis[s] * ew[e] * dis[d];
    int pos = atomicAdd(&cur[s], 1);
    csr_dst[pos] = d;
    csr_w[pos] = w;
}

// ============ K3e: fused diffusion gather + cosine + log-degree ============
// 32 lanes per node (float4 row I/O), 8 nodes per block: halves the wave count
// vs 64-lane/node (2x latency hiding for the csr->shfl->gather dep chain) and
// doubles csr-load lane utilization (avg deg ~6 of 32 active vs 6 of 64).
// Bijective swizzle: 12500 blocks = 4 * 3125.
__global__ __launch_bounds__(256) void k_gather_cos(
    const int* __restrict__ rowstart, const float* __restrict__ deg_c,
    const int* __restrict__ csr_dst, const float* __restrict__ csr_w,
    const float* __restrict__ x, float* __restrict__ raw0, float* __restrict__ raw2)
{
    int blk = blockIdx.x;                        // 12500 blocks
    int grp = (blk & 3) * 3125 + (blk >> 2);     // bijective [0,12500)
    int sub = threadIdx.x >> 5;                  // 0..7 (node within block)
    int lane = threadIdx.x & 31;                 // float4 column
    int node = grp * 8 + sub;
    int start = rowstart[node];
    int deg = (int)deg_c[node];
    const float4* xp = (const float4*)x;
    float4 xn = xp[(size_t)node * 32 + lane];
    float4 acc = {0.f, 0.f, 0.f, 0.f};
    for (int base = 0; base < deg; base += 32) {
        int rem = deg - base; if (rem > 32) rem = 32;
        int md = 0; float mw = 0.f;
        if (lane < rem) {
            md = csr_dst[start + base + lane];
            mw = csr_w[start + base + lane];
        }
        int e = 0;
        for (; e + 4 <= rem; e += 4) {
            int d0 = __shfl(md, e, 32),   d1 = __shfl(md, e+1, 32);
            int d2 = __shfl(md, e+2, 32), d3 = __shfl(md, e+3, 32);
            float w0 = __shfl(mw, e, 32),   w1 = __shfl(mw, e+1, 32);
            float w2 = __shfl(mw, e+2, 32), w3 = __shfl(mw, e+3, 32);
            float4 v0 = xp[(size_t)d0 * 32 + lane];
            float4 v1 = xp[(size_t)d1 * 32 + lane];
            float4 v2 = xp[(size_t)d2 * 32 + lane];
            float4 v3 = xp[(size_t)d3 * 32 + lane];
            acc.x += w0*v0.x; acc.y += w0*v0.y; acc.z += w0*v0.z; acc.w += w0*v0.w;
            acc.x += w1*v1.x; acc.y += w1*v1.y; acc.z += w1*v1.z; acc.w += w1*v1.w;
            acc.x += w2*v2.x; acc.y += w2*v2.y; acc.z += w2*v2.z; acc.w += w2*v2.w;
            acc.x += w3*v3.x; acc.y += w3*v3.y; acc.z += w3*v3.z; acc.w += w3*v3.w;
        }
        for (; e < rem; e++) {
            int d = __shfl(md, e, 32);
            float w = __shfl(mw, e, 32);
            float4 v = xp[(size_t)d * 32 + lane];
            acc.x += w*v.x; acc.y += w*v.y; acc.z += w*v.z; acc.w += w*v.w;
        }
    }
    float dot = xn.x*acc.x + xn.y*acc.y + xn.z*acc.z + xn.w*acc.w;
    float nx  = xn.x*xn.x + xn.y*xn.y + xn.z*xn.z + xn.w*xn.w;
    float nd  = acc.x*acc.x + acc.y*acc.y + acc.z*acc.z + acc.w*acc.w;
    #pragma unroll
    for (int off = 16; off; off >>= 1) {
        dot += __shfl_xor(dot, off, 32);
        nx  += __shfl_xor(nx,  off, 32);
        nd  += __shfl_xor(nd,  off, 32);
    }
    if (lane == 0) {
        raw2[node] = dot / ((sqrtf(nx) + 1e-6f) * (sqrtf(nd) + 1e-6f));
        raw0[node] = logf((float)deg + 1.0f);
    }
}

// ============ K4: per-node feat MLP (register-blocked GEMM) ============
#define XSTR 132
__global__ __launch_bounds__(256) void k_node(
    const float* __restrict__ x,
    const float* __restrict__ W1, const float* __restrict__ b1,
    const float* __restrict__ W2, const float* __restrict__ b2,
    float* __restrict__ raw1)
{
    __shared__ float xs[64 * XSTR]; // 33.8 KB
    int wave = threadIdx.x >> 6, lane = threadIdx.x & 63;
    int ng = lane >> 4, jg = lane & 15;
    int blockBase = blockIdx.x * 64;

    #pragma unroll
    for (int it = 0; it < 8; it++) {
        int s = threadIdx.x + 256 * it;
        int row = s >> 5, c4 = s & 31;
        int gn = blockBase + row; if (gn >= NN) gn = NN - 1;
        *(float4*)(xs + row * XSTR + c4 * 4) =
            *(const float4*)(x + (size_t)gn * DD + c4 * 4);
    }
    __syncthreads();

    const float* xw = xs + (wave * 16 + ng * 4) * XSTR;
    int j0 = jg * 8;
    float acc[4][8];
    #pragma unroll
    for (int i = 0; i < 4; i++)
        #pragma unroll
        for (int jj = 0; jj < 8; jj++) acc[i][jj] = 0.f;

    for (int k = 0; k < DD; k += 4) {
        float4 xv[4];
        #pragma unroll
        for (int i = 0; i < 4; i++) xv[i] = *(const float4*)(xw + i * XSTR + k);
        float4 wv[4][2];
        #pragma unroll
        for (int kk = 0; kk < 4; kk++) {
            wv[kk][0] = *(const float4*)(W1 + (k + kk) * DD + j0);
            wv[kk][1] = *(const float4*)(W1 + (k + kk) * DD + j0 + 4);
        }
        #pragma unroll
        for (int i = 0; i < 4; i++) {
            const float xe[4] = {xv[i].x, xv[i].y, xv[i].z, xv[i].w};
            #pragma unroll
            for (int kk = 0; kk < 4; kk++) {
                acc[i][0] += xe[kk] * wv[kk][0].x;
                acc[i][1] += xe[kk] * wv[kk][0].y;
                acc[i][2] += xe[kk] * wv[kk][0].z;
                acc[i][3] += xe[kk] * wv[kk][0].w;
                acc[i][4] += xe[kk] * wv[kk][1].x;
                acc[i][5] += xe[kk] * wv[kk][1].y;
                acc[i][6] += xe[kk] * wv[kk][1].z;
                acc[i][7] += xe[kk] * wv[kk][1].w;
            }
        }
    }

    float4 b1a = *(const float4*)(b1 + j0), b1b = *(const float4*)(b1 + j0 + 4);
    float4 w2a = *(const float4*)(W2 + j0), w2b = *(const float4*)(W2 + j0 + 4);
    const float b1v[8] = {b1a.x,b1a.y,b1a.z,b1a.w, b1b.x,b1b.y,b1b.z,b1b.w};
    const float w2v[8] = {w2a.x,w2a.y,w2a.z,w2a.w, w2b.x,w2b.y,w2b.z,w2b.w};
    float bias2 = b2[0];
    #pragma unroll
    for (int i = 0; i < 4; i++) {
        float p = 0.f;
        #pragma unroll
        for (int jj = 0; jj < 8; jj++)
            p += fmaxf(acc[i][jj] + b1v[jj], 0.f) * w2v[jj];
        p += __shfl_xor(p, 1, 64);
        p += __shfl_xor(p, 2, 64);
        p += __shfl_xor(p, 4, 64);
        p += __shfl_xor(p, 8, 64);
        int node = blockBase + wave * 16 + ng * 4 + i;
        if (jg == 0 && node < NN) raw1[node] = p + bias2;
    }
}

// ============ K5: block-level f64 partial sums (sum, sumsq) x3 ============
__global__ __launch_bounds__(256) void k_reduce(
    const float* __restrict__ r0, const float* __restrict__ r1,
    const float* __restrict__ r2, double* __restrict__ partials)
{
    __shared__ double sd[256];
    double s[6] = {0,0,0,0,0,0};
    for (int n = blockIdx.x * 256 + threadIdx.x; n < NN; n += 256 * NRED) {
        double v0 = r0[n], v1 = r1[n], v2 = r2[n];
        s[0] += v0; s[1] += v0*v0;
        s[2] += v1; s[3] += v1*v1;
        s[4] += v2; s[5] += v2*v2;
    }
    for (int q = 0; q < 6; q++) {
        sd[threadIdx.x] = s[q];
        __syncthreads();
        for (int off = 128; off; off >>= 1) {
            if (threadIdx.x < off) sd[threadIdx.x] += sd[threadIdx.x + off];
            __syncthreads();
        }
        if (threadIdx.x == 0) partials[blockIdx.x * 6 + q] = sd[0];
        __syncthreads();
    }
}

// ============ K6: final stats -> mean, 1/(std+eps) per view ============
__global__ __launch_bounds__(256) void k_stats(const double* __restrict__ partials,
                                               float* __restrict__ stats)
{
    __shared__ double sd[256];
    __shared__ double sums[6];
    for (int q = 0; q < 6; q++) {
        sd[threadIdx.x] = (threadIdx.x < NRED) ? partials[threadIdx.x * 6 + q] : 0.0;
        __syncthreads();
        for (int off = 128; off; off >>= 1) {
            if (threadIdx.x < off) sd[threadIdx.x] += sd[threadIdx.x + off];
            __syncthreads();
        }
        if (threadIdx.x == 0) sums[q] = sd[0];
        __syncthreads();
    }
    if (threadIdx.x == 0) {
        for (int i = 0; i < 3; i++) {
            double sum = sums[2*i], sq = sums[2*i+1];
            double mean = sum / NN;
            double var = (sq - sum * sum / NN) / (NN - 1);
            double sdv = sqrt(var > 0 ? var : 0);
            stats[2*i]   = (float)mean;
            stats[2*i+1] = (float)(1.0 / (sdv + 1e-6));
        }
    }
}

// ============ K8: per-graph score (fused) + top-K bitonic sort ============
__global__ __launch_bounds__(1024) void k_topk(
    const float* __restrict__ r0, const float* __restrict__ r1,
    const float* __restrict__ r2, const float* __restrict__ stats,
    const float* __restrict__ vw, float* __restrict__ score,
    int* __restrict__ keep, int* __restrict__ new_id, float* __restrict__ obatch)
{
    __shared__ unsigned long long keys[2048];
    int b = blockIdx.x;
    unsigned t = threadIdx.x;
    float m0 = stats[0], is0 = stats[1];
    float m1 = stats[2], is1 = stats[3];
    float m2 = stats[4], is2 = stats[5];
    float v0 = vw[0], v1 = vw[1], v2 = vw[2];
    for (unsigned i = t; i < 2048; i += 1024) {
        unsigned long long kk = 0ull;
        if (i < NPG) {
            int n = b * NPG + (int)i;
            float z0 = (r0[n] - m0) * is0;
            float z1 = (r1[n] - m1) * is1;
            float z2 = (r2[n] - m2) * is2;
            float r = z0 * v0 + z1 * v1 + z2 * v2;
            float sc = 1.f / (1.f + expf(-r));
            score[n] = sc;
            kk = ((unsigned long long)__float_as_uint(sc) << 32)
               | (unsigned long long)(0xFFFFFFFFu - i);
        }
        keys[i] = kk;
    }
    __syncthreads();
    for (unsigned k = 2; k <= 2048; k <<= 1) {
        for (unsigned j = k >> 1; j > 0; j >>= 1) {
            unsigned i = ((t & ~(j - 1)) << 1) | (t & (j - 1));
            unsigned p = i | j;
            unsigned long long a = keys[i], c = keys[p];
            bool up = ((i & k) == 0);
            if ((a < c) == up) { keys[i] = c; keys[p] = a; }
            __syncthreads();
        }
    }
    if (t < KK) {
        unsigned long long kk = keys[t];
        unsigned li = 0xFFFFFFFFu - (unsigned)(kk & 0xFFFFFFFFu);
        int node = b * NPG + (int)li;
        int j = b * KK + (int)t;
        keep[j] = node;
        new_id[node] = j;
        obatch[j] = (float)b;
    }
}

// ============ K9: out_x = x[keep] * score[keep] (float4, 8 rows/block) ============
__global__ __launch_bounds__(256) void k_outx(
    const float* __restrict__ x, const float* __restrict__ score,
    const int* __restrict__ keep, float* __restrict__ out_x)
{
    int r = blockIdx.x * 8 + (threadIdx.x >> 5);   // kept-node row
    int c = threadIdx.x & 31;                      // float4 column
    if (r >= NKEEP) return;
    int node = keep[r];
    float s = score[node];
    float4 v = *(const float4*)(x + (size_t)node * DD + c * 4);
    float4 o; o.x = v.x*s; o.y = v.y*s; o.z = v.z*s; o.w = v.w*s;
    *(float4*)(out_x + (size_t)r * DD + c * 4) = o;
}

// ============ K10: fused edge mask + new edge_index + masked edge_attr ============
__global__ __launch_bounds__(256) void k_edges_attr(
    const int* __restrict__ src, const int* __restrict__ dst,
    const int* __restrict__ new_id, const float* __restrict__ edge_attr,
    float* __restrict__ oei, float* __restrict__ emask, float* __restrict__ oea)
{
    int e = blockIdx.x * 256 + threadIdx.x;
    if (e >= EE) return;
    int ns = new_id[src[e]], nd = new_id[dst[e]];
    bool m = (ns >= 0) && (nd >= 0);
    float mm = m ? 1.f : 0.f;
    const float4* in4 = (const float4*)edge_attr;
    float4* out4 = (float4*)oea;
    #pragma unroll
    for (int c = 0; c < 4; c++) {
        float4 v = in4[(size_t)e * 4 + c];
        float4 o; o.x = v.x*mm; o.y = v.y*mm; o.z = v.z*mm; o.w = v.w*mm;
        out4[(size_t)e * 4 + c] = o;
    }
    oei[e]      = m ? (float)ns : 0.f;
    oei[EE + e] = m ? (float)nd : 0.f;
    emask[e]    = mm;
}

extern "C" void kernel_launch(void* const* d_in, const int* in_sizes, int n_in,
                              void* d_out, int out_size, void* d_ws, size_t ws_size,
                              hipStream_t stream) {
    const float* x         = (const float*)d_in[0];
    const int*   edge_idx  = (const int*)d_in[1];
    const float* edge_attr = (const float*)d_in[2];
    const float* W1  = (const float*)d_in[4];
    const float* b1  = (const float*)d_in[5];
    const float* W2  = (const float*)d_in[6];
    const float* b2  = (const float*)d_in[7];
    const float* We1 = (const float*)d_in[8];
    const float* be1 = (const float*)d_in[9];
    const float* We2 = (const float*)d_in[10];
    const float* be2 = (const float*)d_in[11];
    const float* vw  = (const float*)d_in[12];

    const int* src = edge_idx;
    const int* dst = edge_idx + EE;

    float* out    = (float*)d_out;
    float* out_x  = out;
    float* oei    = out + OFF_OEI;
    float* oea    = out + OFF_OEA;
    float* obatch = out + OFF_OBATCH;
    float* emask  = out + OFF_EMASK;

    // scratch inside d_out (dead before any output writer runs)
    int*   csr_dst   = (int*)(out + 12800000);    // 600k
    float* csr_w     = out + 13400000;            // 600k
    int*   rowstart  = (int*)(out + 14000000);    // 100k
    int*   cur       = (int*)(out + 14100000);    // 100k
    int*   scanned   = (int*)(out + 14200000);    // 100k
    int*   blocksums = (int*)(out + 14300000);    // 256

    // workspace layout (floats) — ~5.9 MB total
    float* ws     = (float*)d_ws;
    float* ew     = ws;                     // 600000
    float* deg_w  = ws + 600000;            // 100000
    float* deg_c  = ws + 700000;            // 100000 (adjacent to deg_w)
    float* dis    = ws + 800000;            // 100000
    float* score  = ws + 900000;            // 100000
    float* raw0   = ws + 1000000;           // 100000
    float* raw1   = ws + 1100000;           // 100000
    float* raw2   = ws + 1200000;           // 100000
    int*   keep   = (int*)(ws + 1300000);   // 50000
    int*   new_id = (int*)(ws + 1350000);   // 100000
    double* partials = (double*)(ws + 1450000); // NRED*6 doubles
    float* stats  = ws + 1450000 + 2 * 6 * NRED; // 6 floats

    hipMemsetAsync(deg_w, 0, 2 * NN * sizeof(float), stream); // deg_w + deg_c

    // two half-range launches: per-dispatch ~41us -> unblocks rocprof top-5
    const int HE = EE / 2;  // 300000
    k_edge_mlp<<<(HE + 255) / 256, 256, 0, stream>>>(edge_attr, src, We1, be1,
                                                     We2, be2, ew, deg_w, deg_c, HE);
    k_edge_mlp<<<(HE + 255) / 256, 256, 0, stream>>>(edge_attr + (size_t)HE * EAD,
                                                     src + HE, We1, be1, We2, be2,
                                                     ew + HE, deg_w, deg_c, HE);
    // CSR build (k_cursor also computes dis and inits new_id = -1)
    k_scan_block<<<SCAN_NB, 1024, 0, stream>>>(deg_c, scanned, blocksums);
    k_scan_top<<<1, 128, 0, stream>>>(blocksums);
    k_cursor<<<(NN + 255) / 256, 256, 0, stream>>>(scanned, blocksums, deg_w,
                                                   rowstart, cur, dis, new_id);
    k_scatter<<<(EE + 255) / 256, 256, 0, stream>>>(src, dst, ew, dis, cur, csr_dst, csr_w);
    // fused diffusion gather + cosine + log-degree (x_diff never materialized)
    k_gather_cos<<<NN / 8, 256, 0, stream>>>(rowstart, deg_c, csr_dst,
                                             csr_w, x, raw0, raw2);
    k_node<<<(NN + 63) / 64, 256, 0, stream>>>(x, W1, b1, W2, b2, raw1);
    k_reduce<<<NRED, 256, 0, stream>>>(raw0, raw1, raw2, partials);
    k_stats<<<1, 256, 0, stream>>>(partials, stats);
    k_topk<<<BB, 1024, 0, stream>>>(raw0, raw1, raw2, stats, vw, score,
                                    keep, new_id, obatch);
    k_outx<<<(NKEEP + 7) / 8, 256, 0, stream>>>(x, score, keep, out_x);
    k_edges_attr<<<(EE + 255) / 256, 256, 0, stream>>>(src, dst, new_id,
                                                       edge_attr, oei, emask, oea);
}